// Round 1
// baseline (1358.864 us; speedup 1.0000x reference)
//
#include <hip/hip_runtime.h>

// DGCNN on MI355X — round 1: fp32, structurally optimized.
//   N=100000 nodes, K=16 neighbors, E=1.6M edges.
// Key identities used:
//   concat(a, b-a) @ W + bias = a @ (Wt - Wb) + b @ Wb + bias   (Wt=top half rows, Wb=bottom)
//   conv2 gathers h1 with NODE ids -> only h1[0:N] rows are needed (16x less conv1 work)
//   h2 [E,128] never materialized: fused gather->relu->GEMM(W4)->relu->max_K->MLP(W5,W6)

#define NN 100000
#define KNB 16
#define EE (NN * KNB)
#define ESTR 132   // LDS leading-dim pad for the 64x128 edge tile (16B-aligned, 2-way banks)

// ---------------- K1: A1 = x@(W1t-W1b)+b1, B1 = x@W1b  ([N,16] -> [N,64] x2) ----
__global__ __launch_bounds__(256) void k1_kernel(
    const float* __restrict__ x, const float* __restrict__ W1,
    const float* __restrict__ b1, float* __restrict__ A1, float* __restrict__ B1)
{
    int gid = blockIdx.x * 256 + threadIdx.x;
    int n = gid >> 6;
    int j = gid & 63;
    const float* xr = x + n * 16;
    float acc_a = b1[j];
    float acc_b = 0.0f;
#pragma unroll
    for (int k = 0; k < 16; ++k) {
        float xv = xr[k];
        float wt = W1[k * 64 + j];
        float wb = W1[(16 + k) * 64 + j];
        acc_a = fmaf(xv, wt - wb, acc_a);
        acc_b = fmaf(xv, wb, acc_b);
    }
    A1[n * 64 + j] = acc_a;
    B1[n * 64 + j] = acc_b;
}

// ---------------- K2: for i in [0,N): h1[i] = relu(relu(A1[i/16]+B1[col[i]]) @ W2 + b2)
//                      A3[i] = h1[i]@(W3t-W3b)+b3 ; B3[i] = h1[i]@W3b  ------------
__global__ __launch_bounds__(256) void k2_kernel(
    const int* __restrict__ col,
    const float* __restrict__ A1, const float* __restrict__ B1,
    const float* __restrict__ W2, const float* __restrict__ b2,
    const float* __restrict__ W3, const float* __restrict__ b3,
    float* __restrict__ A3, float* __restrict__ B3)
{
    __shared__ float sh_t[4][64];
    __shared__ float sh_h[4][64];
    const int t = threadIdx.x;
    const int le = t >> 6;
    const int j = t & 63;
    const int e = blockIdx.x * 4 + le;     // h1-row index, < N
    const int n = e >> 4;                  // row[e] = e//16 (row = repeat(arange(N),16))
    const int c = col[e];
    float tv = A1[n * 64 + j] + B1[(size_t)c * 64 + j];
    sh_t[le][j] = fmaxf(tv, 0.0f);
    __syncthreads();
    float acc = b2[j];
#pragma unroll 8
    for (int k = 0; k < 64; ++k)
        acc = fmaf(sh_t[le][k], W2[k * 64 + j], acc);
    sh_h[le][j] = fmaxf(acc, 0.0f);
    __syncthreads();
    float aa0 = b3[j], aa1 = b3[j + 64];
    float ab0 = 0.0f, ab1 = 0.0f;
#pragma unroll 4
    for (int k = 0; k < 64; ++k) {
        float hv = sh_h[le][k];
        float w00 = W3[k * 128 + j];
        float w01 = W3[k * 128 + j + 64];
        float w10 = W3[(64 + k) * 128 + j];
        float w11 = W3[(64 + k) * 128 + j + 64];
        aa0 = fmaf(hv, w00 - w10, aa0);
        aa1 = fmaf(hv, w01 - w11, aa1);
        ab0 = fmaf(hv, w10, ab0);
        ab1 = fmaf(hv, w11, ab1);
    }
    size_t eo = (size_t)e * 128;
    A3[eo + j]      = aa0;
    A3[eo + j + 64] = aa1;
    B3[eo + j]      = ab0;
    B3[eo + j + 64] = ab1;
}

// ---------------- K3: fused main kernel. Block = 256 thr, 4 nodes = 64 edges. ----
// pre[e] = relu(A3[e/16] + B3[col[e]])            (gather, LDS tile 64x128)
// h2[e]  = relu(pre[e] @ W4 + b4)                 (register-tiled fp32 GEMM)
// g[n]   = max over the node's 16 edges           (LDS reduce)
// out[n] = relu(g[n] @ W5 + b5) @ W6 + b6         (fused epilogue)
__global__ __launch_bounds__(256) void k3_kernel(
    const int* __restrict__ col,
    const float* __restrict__ A3, const float* __restrict__ B3,
    const float* __restrict__ W4, const float* __restrict__ b4,
    const float* __restrict__ W5, const float* __restrict__ b5,
    const float* __restrict__ W6, const float* __restrict__ b6,
    float* __restrict__ out)
{
    __shared__ float sh_e[64 * ESTR];   // 33 KB: edge tile / later t1 + W6 stage
    __shared__ float sh_w[32 * 128];    // 16 KB: W4/W5 k-chunk stage / later pm[16][128]
    __shared__ float sh_a[512];         // 2 KB: A3 rows of 4 nodes / later g[4][128]

    const int t = threadIdx.x;
    const int node0 = blockIdx.x * 4;
    const int e0 = node0 * KNB;         // block's first edge

    // stage A3 rows of this block's 4 nodes (512 floats)
    sh_a[t]       = A3[(size_t)node0 * 128 + t];
    sh_a[t + 256] = A3[(size_t)node0 * 128 + t + 256];
    __syncthreads();

    // ---- phase 1: build edge tile: sh_e[le][j] = relu(A3[node]+B3[col]) ----
    {
        const int le = t >> 2;          // edge 0..63
        const int part = t & 3;         // 32-float slab
        const int c = col[e0 + le];
        const float* brow = B3 + (size_t)c * 128 + part * 32;
        const float* arow = sh_a + (le >> 4) * 128 + part * 32;
        float* erow = sh_e + le * ESTR + part * 32;
#pragma unroll
        for (int i = 0; i < 32; i += 4) {
            float4 bv = *(const float4*)(brow + i);
            float4 av = *(const float4*)(arow + i);
            float4 r;
            r.x = fmaxf(av.x + bv.x, 0.0f);
            r.y = fmaxf(av.y + bv.y, 0.0f);
            r.z = fmaxf(av.z + bv.z, 0.0f);
            r.w = fmaxf(av.w + bv.w, 0.0f);
            *(float4*)(erow + i) = r;
        }
    }
    __syncthreads();

    // ---- phase 2: [64,128] @ W4[128,128], register tile 4 edges x 8 cols ----
    const int ty = t >> 4, tx = t & 15;
    const int je0 = tx * 8;
    const int ee0 = ty * 4;
    float acc[4][8];
#pragma unroll
    for (int i = 0; i < 4; ++i)
#pragma unroll
        for (int jj = 0; jj < 8; ++jj) acc[i][jj] = 0.0f;

    for (int kc = 0; kc < 4; ++kc) {
        {   // stage W4 rows kc*32..kc*32+31 into sh_w (coalesced float4)
            const float4* src4 = (const float4*)(W4 + kc * 32 * 128);
            float4* dst4 = (float4*)sh_w;
#pragma unroll
            for (int r = 0; r < 4; ++r) dst4[t + r * 256] = src4[t + r * 256];
        }
        __syncthreads();
#pragma unroll
        for (int kk = 0; kk < 32; kk += 4) {
            float4 h4[4];
#pragma unroll
            for (int i = 0; i < 4; ++i)
                h4[i] = *(const float4*)&sh_e[(ee0 + i) * ESTR + kc * 32 + kk];
#pragma unroll
            for (int u = 0; u < 4; ++u) {
                float4 w0 = *(const float4*)&sh_w[(kk + u) * 128 + je0];
                float4 w1 = *(const float4*)&sh_w[(kk + u) * 128 + je0 + 4];
                float wv[8] = {w0.x, w0.y, w0.z, w0.w, w1.x, w1.y, w1.z, w1.w};
#pragma unroll
                for (int i = 0; i < 4; ++i) {
                    float hv = (u == 0) ? h4[i].x : (u == 1) ? h4[i].y
                             : (u == 2) ? h4[i].z : h4[i].w;
#pragma unroll
                    for (int jj = 0; jj < 8; ++jj)
                        acc[i][jj] = fmaf(hv, wv[jj], acc[i][jj]);
                }
            }
        }
        __syncthreads();
    }

    // ---- phase 3: +b4, relu, max over this thread's 4 edges (same node), reduce ----
    float* pm = sh_w;                   // pm[16][128] partial maxima (8 KB)
    {
#pragma unroll
        for (int jj = 0; jj < 8; ++jj) {
            float b = b4[je0 + jj];
            float m = 0.0f;             // relu floor: max_k relu(v_k) == max(0, max_k v_k)
#pragma unroll
            for (int i = 0; i < 4; ++i) m = fmaxf(m, acc[i][jj] + b);
            pm[ty * 128 + je0 + jj] = m;
        }
    }
    __syncthreads();
    float* sh_g = sh_a;                 // g[4][128]
#pragma unroll
    for (int r = 0; r < 2; ++r) {
        int idx = t + r * 256;
        int ni = idx >> 7, j = idx & 127;
        float m = pm[(ni * 4 + 0) * 128 + j];
        m = fmaxf(m, pm[(ni * 4 + 1) * 128 + j]);
        m = fmaxf(m, pm[(ni * 4 + 2) * 128 + j]);
        m = fmaxf(m, pm[(ni * 4 + 3) * 128 + j]);
        sh_g[idx] = m;
    }
    __syncthreads();

    // ---- phase 4: t1 = relu(g @ W5 + b5)  (512 outputs, 2/thread) ----
    float t1acc[2];
#pragma unroll
    for (int r = 0; r < 2; ++r) {
        int idx = t + r * 256;
        t1acc[r] = b5[idx & 127];
    }
    for (int kc = 0; kc < 4; ++kc) {
        {   // stage W5 chunk into sh_w
            const float4* src4 = (const float4*)(W5 + kc * 32 * 128);
            float4* dst4 = (float4*)sh_w;
#pragma unroll
            for (int r = 0; r < 4; ++r) dst4[t + r * 256] = src4[t + r * 256];
        }
        __syncthreads();
#pragma unroll
        for (int r = 0; r < 2; ++r) {
            int idx = t + r * 256;
            int ni = idx >> 7, j = idx & 127;
#pragma unroll 8
            for (int kk = 0; kk < 32; ++kk)
                t1acc[r] = fmaf(sh_g[ni * 128 + kc * 32 + kk],
                                sh_w[kk * 128 + j], t1acc[r]);
        }
        __syncthreads();
    }
    float* sh_t1 = sh_e;                // t1[4][128] at sh_e[0..511]
    float* sh_w6 = sh_e + 512;          // W6 stage [128][40] = 5120 floats
#pragma unroll
    for (int r = 0; r < 2; ++r) {
        int idx = t + r * 256;
        sh_t1[idx] = fmaxf(t1acc[r], 0.0f);
    }
#pragma unroll
    for (int r = 0; r < 20; ++r)
        sh_w6[t + r * 256] = W6[t + r * 256];
    __syncthreads();

    // ---- phase 5: out = t1 @ W6 + b6  (4x40 outputs) ----
    if (t < 160) {
        int ni = t / 40, j = t % 40;
        float acc6 = b6[j];
#pragma unroll 8
        for (int k = 0; k < 128; ++k)
            acc6 = fmaf(sh_t1[ni * 128 + k], sh_w6[k * 40 + j], acc6);
        out[(size_t)(node0 + ni) * 40 + j] = acc6;
    }
}

extern "C" void kernel_launch(void* const* d_in, const int* in_sizes, int n_in,
                              void* d_out, int out_size, void* d_ws, size_t ws_size,
                              hipStream_t stream)
{
    const float* x  = (const float*)d_in[0];
    const int* ei   = (const int*)d_in[1];
    const int* col  = ei + EE;              // edge_index[1,:]
    const float* W1 = (const float*)d_in[2];
    const float* b1 = (const float*)d_in[3];
    const float* W2 = (const float*)d_in[4];
    const float* b2 = (const float*)d_in[5];
    const float* W3 = (const float*)d_in[6];
    const float* b3 = (const float*)d_in[7];
    const float* W4 = (const float*)d_in[8];
    const float* b4 = (const float*)d_in[9];
    const float* W5 = (const float*)d_in[10];
    const float* b5 = (const float*)d_in[11];
    const float* W6 = (const float*)d_in[12];
    const float* b6 = (const float*)d_in[13];
    float* out = (float*)d_out;

    float* A1 = (float*)d_ws;                    // [N,64]
    float* B1 = A1 + (size_t)NN * 64;            // [N,64]
    float* A3 = B1 + (size_t)NN * 64;            // [N,128]
    float* B3 = A3 + (size_t)NN * 128;           // [N,128]  (total 153.6 MB)

    k1_kernel<<<NN * 64 / 256, 256, 0, stream>>>(x, W1, b1, A1, B1);
    k2_kernel<<<NN / 4, 256, 0, stream>>>(col, A1, B1, W2, b2, W3, b3, A3, B3);
    k3_kernel<<<NN / 4, 256, 0, stream>>>(col, A3, B3, W4, b4, W5, b5, W6, b6, out);
}

// Round 2
// 974.652 us; speedup vs baseline: 1.3942x; 1.3942x over previous
//
#include <hip/hip_runtime.h>

// DGCNN on MI355X — round 2: scalar-weight (wave-uniform s_load) GEMMs.
// R1 post-mortem: LDS pipe was the bottleneck (12 ds_read_b128 per 128 FMA,
// 1.4e8 bank-conflict cycles). New structure: each thread owns 1 row x 32
// cols; row activations via per-lane ds_read_b128 (1 per 4k), weights via
// wave-uniform loads (readfirstlane'd column group -> s_load, SMEM pipe).
//   concat(a, b-a) @ W + bias = a @ (Wt-Wb) + b @ Wb + bias
//   conv2 gathers h1 with NODE ids -> only h1[0:N] rows needed
//   h2 [E,128] never materialized; g=[N,128] round-trips through ws.

#define NN 100000
#define KNB 16
#define EE (NN * KNB)
#define ESTR 132   // 128+4 word row stride: b128 lanes tile banks perfectly
#define HSTR 68    // 64+4 for the 64-wide tiles in k2

// ---------------- K1: A1 = x@(W1t-W1b)+b1, B1 = x@W1b  ([N,16] -> [N,64] x2) ----
__global__ __launch_bounds__(256) void k1_kernel(
    const float* __restrict__ x, const float* __restrict__ W1,
    const float* __restrict__ b1, float* __restrict__ A1, float* __restrict__ B1)
{
    int gid = blockIdx.x * 256 + threadIdx.x;
    int n = gid >> 6;
    int j = gid & 63;
    const float* xr = x + n * 16;
    float acc_a = b1[j];
    float acc_b = 0.0f;
#pragma unroll
    for (int k = 0; k < 16; ++k) {
        float xv = xr[k];
        float wt = W1[k * 64 + j];
        float wb = W1[(16 + k) * 64 + j];
        acc_a = fmaf(xv, wt - wb, acc_a);
        acc_b = fmaf(xv, wb, acc_b);
    }
    A1[n * 64 + j] = acc_a;
    B1[n * 64 + j] = acc_b;
}

// ---------------- K2: rows i in [0,N): h1 = relu(relu(A1[i/16]+B1[col[i]])@W2+b2)
//                      A3[i] = h1@(W3t-W3b)+b3 ; B3[i] = h1@W3b ------------------
// Block: 64 rows x 256 thr. Thread = (row = t&63, colgroup = t>>6, wave-uniform).
__global__ __launch_bounds__(256) void k2_kernel(
    const int* __restrict__ col,
    const float* __restrict__ A1, const float* __restrict__ B1,
    const float* __restrict__ W2, const float* __restrict__ b2,
    const float* __restrict__ W3, const float* __restrict__ b3,
    float* __restrict__ A3, float* __restrict__ B3)
{
    __shared__ float sh_t[64 * HSTR];
    __shared__ float sh_h[64 * HSTR];
    const int t = threadIdx.x;
    const int row = t & 63;
    const int part = t >> 6;
    const int e = blockIdx.x * 64 + row;        // tail rows >= N read garbage, stores guarded
    // phase A: sh_t[row] = relu(A1[e/16] + B1[col[e]])
    {
        int n = e >> 4;
        int c = col[e];
        const float* ar = A1 + (size_t)n * 64 + part * 16;
        const float* br = B1 + (size_t)c * 64 + part * 16;
        float* dr = sh_t + row * HSTR + part * 16;
#pragma unroll
        for (int i = 0; i < 16; i += 4) {
            float4 a = *(const float4*)(ar + i);
            float4 b = *(const float4*)(br + i);
            float4 r;
            r.x = fmaxf(a.x + b.x, 0.0f); r.y = fmaxf(a.y + b.y, 0.0f);
            r.z = fmaxf(a.z + b.z, 0.0f); r.w = fmaxf(a.w + b.w, 0.0f);
            *(float4*)(dr + i) = r;
        }
    }
    __syncthreads();
    const int cg = __builtin_amdgcn_readfirstlane(part);   // wave-uniform
    // phase B: h = relu(sh_t @ W2 + b2), this thread: 16 cols cg*16..+15
    {
        float acc[16];
#pragma unroll
        for (int j = 0; j < 16; ++j) acc[j] = 0.0f;
        const float* hr = sh_t + row * HSTR;
        for (int k0 = 0; k0 < 64; k0 += 4) {
            float4 h4 = *(const float4*)(hr + k0);
#pragma unroll
            for (int u = 0; u < 4; ++u) {
                float hv = (u == 0) ? h4.x : (u == 1) ? h4.y : (u == 2) ? h4.z : h4.w;
                const float* wr = W2 + (k0 + u) * 64 + cg * 16;   // uniform -> s_load
#pragma unroll
                for (int jq = 0; jq < 4; ++jq) {
                    float4 w = *(const float4*)(wr + jq * 4);
                    acc[jq*4+0] = fmaf(hv, w.x, acc[jq*4+0]);
                    acc[jq*4+1] = fmaf(hv, w.y, acc[jq*4+1]);
                    acc[jq*4+2] = fmaf(hv, w.z, acc[jq*4+2]);
                    acc[jq*4+3] = fmaf(hv, w.w, acc[jq*4+3]);
                }
            }
        }
        const float* bp = b2 + cg * 16;                          // uniform
        float* orow = sh_h + row * HSTR + cg * 16;
#pragma unroll
        for (int j = 0; j < 16; j += 4) {
            float4 b = *(const float4*)(bp + j);
            float4 r;
            r.x = fmaxf(acc[j+0] + b.x, 0.0f); r.y = fmaxf(acc[j+1] + b.y, 0.0f);
            r.z = fmaxf(acc[j+2] + b.z, 0.0f); r.w = fmaxf(acc[j+3] + b.w, 0.0f);
            *(float4*)(orow + j) = r;
        }
    }
    __syncthreads();
    // phase C: A3/B3 cols cg*32..+31
    {
        float aT[32], aB[32];
#pragma unroll
        for (int j = 0; j < 32; ++j) { aT[j] = 0.0f; aB[j] = 0.0f; }
        const float* hr = sh_h + row * HSTR;
        for (int k0 = 0; k0 < 64; k0 += 4) {
            float4 h4 = *(const float4*)(hr + k0);
#pragma unroll
            for (int u = 0; u < 4; ++u) {
                float hv = (u == 0) ? h4.x : (u == 1) ? h4.y : (u == 2) ? h4.z : h4.w;
                const float* wt = W3 + (k0 + u) * 128 + cg * 32;        // uniform
                const float* wb = W3 + (64 + k0 + u) * 128 + cg * 32;   // uniform
#pragma unroll
                for (int jq = 0; jq < 8; ++jq) {
                    float4 w0 = *(const float4*)(wt + jq * 4);
                    float4 w1 = *(const float4*)(wb + jq * 4);
                    aT[jq*4+0] = fmaf(hv, w0.x, aT[jq*4+0]);
                    aT[jq*4+1] = fmaf(hv, w0.y, aT[jq*4+1]);
                    aT[jq*4+2] = fmaf(hv, w0.z, aT[jq*4+2]);
                    aT[jq*4+3] = fmaf(hv, w0.w, aT[jq*4+3]);
                    aB[jq*4+0] = fmaf(hv, w1.x, aB[jq*4+0]);
                    aB[jq*4+1] = fmaf(hv, w1.y, aB[jq*4+1]);
                    aB[jq*4+2] = fmaf(hv, w1.z, aB[jq*4+2]);
                    aB[jq*4+3] = fmaf(hv, w1.w, aB[jq*4+3]);
                }
            }
        }
        if (e < NN) {
            const float* bp = b3 + cg * 32;                     // uniform
            float* Ad = A3 + (size_t)e * 128 + cg * 32;
            float* Bd = B3 + (size_t)e * 128 + cg * 32;
#pragma unroll
            for (int j = 0; j < 32; j += 4) {
                float4 b = *(const float4*)(bp + j);
                float4 ra, rb;
                ra.x = aT[j+0] - aB[j+0] + b.x; ra.y = aT[j+1] - aB[j+1] + b.y;
                ra.z = aT[j+2] - aB[j+2] + b.z; ra.w = aT[j+3] - aB[j+3] + b.w;
                rb.x = aB[j+0]; rb.y = aB[j+1]; rb.z = aB[j+2]; rb.w = aB[j+3];
                *(float4*)(Ad + j) = ra;
                *(float4*)(Bd + j) = rb;
            }
        }
    }
}

// ---------------- K3: gather -> relu -> @W4 -> (+b4, relu folded into) max_K -> g
// Block: 4 nodes = 64 edges. Thread = (edge row = t&63, colgroup = t>>6).
__global__ __launch_bounds__(256) void k3_kernel(
    const int* __restrict__ col,
    const float* __restrict__ A3, const float* __restrict__ B3,
    const float* __restrict__ W4, const float* __restrict__ b4,
    float* __restrict__ g)
{
    __shared__ float sh_a[512];
    __shared__ float sh_e[64 * ESTR];      // 33 KB edge tile, reused for raw h2
    const int t = threadIdx.x;
    const int node0 = blockIdx.x * 4;
    const int e0 = node0 * KNB;
    const int row = t & 63;
    const int part = t >> 6;

    sh_a[t]       = A3[(size_t)node0 * 128 + t];
    sh_a[t + 256] = A3[(size_t)node0 * 128 + t + 256];
    __syncthreads();

    // phase 1: sh_e[row] = relu(A3[node] + B3[col]) ; thread does a 32-float slab
    {
        const int c = col[e0 + row];
        const float* brow = B3 + (size_t)c * 128 + part * 32;
        const float* arow = sh_a + (row >> 4) * 128 + part * 32;
        float* erow = sh_e + row * ESTR + part * 32;
#pragma unroll
        for (int i = 0; i < 32; i += 4) {
            float4 bv = *(const float4*)(brow + i);
            float4 av = *(const float4*)(arow + i);
            float4 r;
            r.x = fmaxf(av.x + bv.x, 0.0f); r.y = fmaxf(av.y + bv.y, 0.0f);
            r.z = fmaxf(av.z + bv.z, 0.0f); r.w = fmaxf(av.w + bv.w, 0.0f);
            *(float4*)(erow + i) = r;
        }
    }
    __syncthreads();

    // phase 2: this thread computes h2[row][cg*32..+31] (pre-bias, pre-relu)
    const int cg = __builtin_amdgcn_readfirstlane(part);
    float acc[32];
#pragma unroll
    for (int j = 0; j < 32; ++j) acc[j] = 0.0f;
    {
        const float* hrow = sh_e + row * ESTR;
        const float* wbase = W4 + cg * 32;
        for (int k0 = 0; k0 < 128; k0 += 4) {
            float4 h4 = *(const float4*)(hrow + k0);
#pragma unroll
            for (int u = 0; u < 4; ++u) {
                float hv = (u == 0) ? h4.x : (u == 1) ? h4.y : (u == 2) ? h4.z : h4.w;
                const float* wr = wbase + (k0 + u) * 128;        // uniform -> s_load
#pragma unroll
                for (int jq = 0; jq < 8; ++jq) {
                    float4 w = *(const float4*)(wr + jq * 4);
                    acc[jq*4+0] = fmaf(hv, w.x, acc[jq*4+0]);
                    acc[jq*4+1] = fmaf(hv, w.y, acc[jq*4+1]);
                    acc[jq*4+2] = fmaf(hv, w.z, acc[jq*4+2]);
                    acc[jq*4+3] = fmaf(hv, w.w, acc[jq*4+3]);
                }
            }
        }
    }
    __syncthreads();                        // all reads of sh_e done
    {
        float* orow = sh_e + row * ESTR + cg * 32;
#pragma unroll
        for (int j = 0; j < 32; j += 4)
            *(float4*)(orow + j) = make_float4(acc[j], acc[j+1], acc[j+2], acc[j+3]);
    }
    __syncthreads();

    // phase 3: g[node] = relu(max_16(raw) + b4)   (max commutes with +b4, relu last)
#pragma unroll
    for (int r = 0; r < 2; ++r) {
        int idx = t + r * 256;
        int ni = idx >> 7, j = idx & 127;
        const float* base = sh_e + (ni * 16) * ESTR + j;
        float m = base[0];
#pragma unroll
        for (int rr = 1; rr < 16; ++rr) m = fmaxf(m, base[rr * ESTR]);
        g[(size_t)(node0 + ni) * 128 + j] = fmaxf(m + b4[j], 0.0f);
    }
}

// ---------------- K4: out = relu(g@W5+b5) @ W6 + b6.  Block: 64 nodes. --------
__global__ __launch_bounds__(256) void k4_kernel(
    const float* __restrict__ g,
    const float* __restrict__ W5, const float* __restrict__ b5,
    const float* __restrict__ W6, const float* __restrict__ b6,
    float* __restrict__ out)
{
    __shared__ float sh_g[64 * ESTR];
    __shared__ float sh_t[64 * ESTR];
    const int t = threadIdx.x;
    const int n0 = blockIdx.x * 64;
    const int row = t & 63;
    const int part = t >> 6;

    {   // stage g rows (clamp tail)
        int gn = n0 + row; if (gn >= NN) gn = NN - 1;
        const float* grow = g + (size_t)gn * 128 + part * 32;
        float* dst = sh_g + row * ESTR + part * 32;
#pragma unroll
        for (int i = 0; i < 32; i += 4)
            *(float4*)(dst + i) = *(const float4*)(grow + i);
    }
    __syncthreads();

    const int cg = __builtin_amdgcn_readfirstlane(part);
    {   // t1 = relu(g @ W5 + b5), cols cg*32..+31
        float acc[32];
#pragma unroll
        for (int j = 0; j < 32; ++j) acc[j] = 0.0f;
        const float* hrow = sh_g + row * ESTR;
        const float* wbase = W5 + cg * 32;
        for (int k0 = 0; k0 < 128; k0 += 4) {
            float4 h4 = *(const float4*)(hrow + k0);
#pragma unroll
            for (int u = 0; u < 4; ++u) {
                float hv = (u == 0) ? h4.x : (u == 1) ? h4.y : (u == 2) ? h4.z : h4.w;
                const float* wr = wbase + (k0 + u) * 128;        // uniform
#pragma unroll
                for (int jq = 0; jq < 8; ++jq) {
                    float4 w = *(const float4*)(wr + jq * 4);
                    acc[jq*4+0] = fmaf(hv, w.x, acc[jq*4+0]);
                    acc[jq*4+1] = fmaf(hv, w.y, acc[jq*4+1]);
                    acc[jq*4+2] = fmaf(hv, w.z, acc[jq*4+2]);
                    acc[jq*4+3] = fmaf(hv, w.w, acc[jq*4+3]);
                }
            }
        }
        const float* bp = b5 + cg * 32;                          // uniform
        float* orow = sh_t + row * ESTR + cg * 32;
#pragma unroll
        for (int j = 0; j < 32; j += 4) {
            float4 b = *(const float4*)(bp + j);
            float4 r;
            r.x = fmaxf(acc[j+0] + b.x, 0.0f); r.y = fmaxf(acc[j+1] + b.y, 0.0f);
            r.z = fmaxf(acc[j+2] + b.z, 0.0f); r.w = fmaxf(acc[j+3] + b.w, 0.0f);
            *(float4*)(orow + j) = r;
        }
    }
    __syncthreads();
    {   // out = t1 @ W6 + b6, this thread: node `row`, cols jb..jb+9
        const int jb = __builtin_amdgcn_readfirstlane(part) * 10;
        float acc6[10];
#pragma unroll
        for (int j = 0; j < 10; ++j) acc6[j] = 0.0f;
        const float* trow = sh_t + row * ESTR;
        for (int k0 = 0; k0 < 128; k0 += 4) {
            float4 h4 = *(const float4*)(trow + k0);
#pragma unroll
            for (int u = 0; u < 4; ++u) {
                float hv = (u == 0) ? h4.x : (u == 1) ? h4.y : (u == 2) ? h4.z : h4.w;
                const float* wr = W6 + (size_t)(k0 + u) * 40 + jb;   // uniform
#pragma unroll
                for (int j = 0; j < 10; ++j)
                    acc6[j] = fmaf(hv, wr[j], acc6[j]);
            }
        }
        int gn = n0 + row;
        if (gn < NN) {
            const float* bp = b6 + jb;                           // uniform
            float* od = out + (size_t)gn * 40 + jb;
#pragma unroll
            for (int j = 0; j < 10; ++j) od[j] = acc6[j] + bp[j];
        }
    }
}

extern "C" void kernel_launch(void* const* d_in, const int* in_sizes, int n_in,
                              void* d_out, int out_size, void* d_ws, size_t ws_size,
                              hipStream_t stream)
{
    const float* x  = (const float*)d_in[0];
    const int* ei   = (const int*)d_in[1];
    const int* col  = ei + EE;              // edge_index[1,:]
    const float* W1 = (const float*)d_in[2];
    const float* b1 = (const float*)d_in[3];
    const float* W2 = (const float*)d_in[4];
    const float* b2 = (const float*)d_in[5];
    const float* W3 = (const float*)d_in[6];
    const float* b3 = (const float*)d_in[7];
    const float* W4 = (const float*)d_in[8];
    const float* b4 = (const float*)d_in[9];
    const float* W5 = (const float*)d_in[10];
    const float* b5 = (const float*)d_in[11];
    const float* W6 = (const float*)d_in[12];
    const float* b6 = (const float*)d_in[13];
    float* out = (float*)d_out;

    float* A1 = (float*)d_ws;                    // [N,64]
    float* B1 = A1 + (size_t)NN * 64;            // [N,64]
    float* A3 = B1 + (size_t)NN * 64;            // [N,128]
    float* B3 = A3 + (size_t)NN * 128;           // [N,128]
    float* g  = A1;                              // [N,128] reuses A1+B1 (dead after k2)

    k1_kernel<<<NN * 64 / 256, 256, 0, stream>>>(x, W1, b1, A1, B1);
    k2_kernel<<<(NN + 63) / 64, 256, 0, stream>>>(col, A1, B1, W2, b2, W3, b3, A3, B3);
    k3_kernel<<<NN / 4, 256, 0, stream>>>(col, A3, B3, W4, b4, g);
    k4_kernel<<<(NN + 63) / 64, 256, 0, stream>>>(g, W5, b5, W6, b6, out);
}